// Round 6
// baseline (11403.893 us; speedup 1.0000x reference)
//
#include <hip/hip_runtime.h>

// Problem dims
constexpr int nB = 32, nS = 512, nI = 512, nH = 1024;
constexpr int N3 = 3 * nH;   // z|r|h concat
constexpr int NW = 32;       // rnn persistent workgroups

typedef __attribute__((ext_vector_type(8))) __bf16 bf16x8;
typedef __attribute__((ext_vector_type(4))) float f32x4;

__device__ __forceinline__ f32x4 mfma16(bf16x8 a, bf16x8 b, f32x4 c) {
  return __builtin_amdgcn_mfma_f32_16x16x32_bf16(a, b, c, 0, 0, 0);
}

// RNE float->bf16
__device__ __forceinline__ unsigned short f2b(float f) {
  unsigned u = __float_as_uint(f);
  u += 0x7fffu + ((u >> 16) & 1u);
  return (unsigned short)(u >> 16);
}
__device__ __forceinline__ float b2f(unsigned short s) {
  return __uint_as_float(((unsigned)s) << 16);
}

// Device-scope (sc1: performed at the Infinity-Cache coherence point) ops.
// Loads are issued as RAW inline-asm so they PIPELINE: LLVM serializes
// __hip_atomic_load chains (one exposed ~650cy IC round-trip per load —
// the R4/R5 bottleneck); asm global_load sc1 issues back-to-back with a
// single s_waitcnt for the whole batch.
__device__ __forceinline__ void cload16_issue(bf16x8* d, const unsigned short* p) {
  asm volatile("global_load_dwordx4 %0, %1, off sc1" : "=&v"(*d) : "v"(p));
}
__device__ __forceinline__ void cload4_issue(unsigned* d, const unsigned short* p) {
  asm volatile("global_load_dword %0, %1, off sc1" : "=&v"(*d) : "v"(p));
}
__device__ __forceinline__ void cwait() {
  asm volatile("s_waitcnt vmcnt(0)" ::: "memory");
  __builtin_amdgcn_sched_barrier(0);   // keep MFMAs from hoisting above the wait
}
__device__ __forceinline__ void cstore4(unsigned short* p, unsigned v) {
  __hip_atomic_store((unsigned*)p, v, __ATOMIC_RELAXED, __HIP_MEMORY_SCOPE_AGENT);
}

// ---------------- prep kernels ----------------

__global__ __launch_bounds__(256) void cast_x_kernel(const float* __restrict__ x,
                                                     unsigned short* __restrict__ xb) {
  size_t i = (size_t)blockIdx.x * 256 + threadIdx.x;
  float4 v = ((const float4*)x)[i];
  uint2 o;
  o.x = (unsigned)f2b(v.x) | ((unsigned)f2b(v.y) << 16);
  o.y = (unsigned)f2b(v.z) | ((unsigned)f2b(v.w) << 16);
  *(uint2*)(xb + i * 4) = o;
}

// out[n][k] = bf16(in[k][n]); in: [K][N] f32. 32x32 LDS tile transpose.
__global__ __launch_bounds__(256) void tcast_kernel(const float* __restrict__ in,
                                                    unsigned short* __restrict__ out,
                                                    int K, int N) {
  __shared__ float tile[32][33];
  int tn = blockIdx.x * 32, tk = blockIdx.y * 32;
  int lx = threadIdx.x & 31, ly = threadIdx.x >> 5;
#pragma unroll
  for (int r = ly; r < 32; r += 8)
    tile[r][lx] = in[(size_t)(tk + r) * N + tn + lx];
  __syncthreads();
#pragma unroll
  for (int r = ly; r < 32; r += 8)
    out[(size_t)(tn + r) * K + tk + lx] = f2b(tile[lx][r]);
}

__global__ __launch_bounds__(256) void bias_cat_kernel(const float* __restrict__ bz,
                                                       const float* __restrict__ br,
                                                       const float* __restrict__ bh,
                                                       float* __restrict__ bc) {
  int i = blockIdx.x * 256 + threadIdx.x;
  if (i >= N3) return;
  bc[i] = (i < nH) ? bz[i] : (i < 2 * nH ? br[i - nH] : bh[i - 2 * nH]);
}

__global__ __launch_bounds__(256) void init_kernel(unsigned short* __restrict__ hb0,
                                                   unsigned* __restrict__ fl) {
  int i = blockIdx.x * 256 + threadIdx.x;   // grid 128 -> 32768 threads
  hb0[i] = 0;                               // H0 = 0 (32*1024 elems)
  if (i < 1024) fl[i] = 0u;                 // barrier flags (NW*16 used)
}

// ---------------- big parallel GEMMs (bf16 MFMA 16x16x32) ----------------
// A fragment: lane l -> A[row0 + (l&15)][k0 + (l>>4)*8 + e]
// B fragment (Bt = B^T, [N][K]): lane l -> B[k0 + (l>>4)*8 + e][n0 + (l&15)]
// D: lane l, reg r -> D[(l>>4)*4 + r][l&15]

__global__ __launch_bounds__(256) void gemm_xp_kernel(
    const unsigned short* __restrict__ A,   // [nB*nS][nI]  (row m = b*nS + s)
    const unsigned short* __restrict__ Bt,  // [N3][nI]
    const float* __restrict__ bias,         // [N3]
    unsigned short* __restrict__ XP) {      // [nS][nB][N3]
  int wave = threadIdx.x >> 6, lane = threadIdx.x & 63;
  int la = lane & 15, ga = lane >> 4;
  int m0 = blockIdx.x * 64 + wave * 16;
  int n0 = blockIdx.y * 64;
  f32x4 z4 = {0.f, 0.f, 0.f, 0.f};
  f32x4 acc[4] = {z4, z4, z4, z4};
  const unsigned short* ap = A + (size_t)(m0 + la) * nI + ga * 8;
  for (int k0 = 0; k0 < nI; k0 += 32) {
    bf16x8 a = *(const bf16x8*)(ap + k0);
#pragma unroll
    for (int j = 0; j < 4; ++j) {
      bf16x8 b = *(const bf16x8*)(Bt + (size_t)(n0 + j * 16 + la) * nI + k0 + ga * 8);
      acc[j] = mfma16(a, b, acc[j]);
    }
  }
#pragma unroll
  for (int j = 0; j < 4; ++j) {
    int col = n0 + j * 16 + la;
    float bv = bias[col];
#pragma unroll
    for (int r = 0; r < 4; ++r) {
      int m = m0 + ga * 4 + r;
      int s = m & (nS - 1), bi = m >> 9;
      XP[((size_t)s * nB + bi) * N3 + col] = f2b(acc[j][r] + bv);
    }
  }
}

__global__ __launch_bounds__(256) void gemm_y_kernel(
    const unsigned short* __restrict__ A,   // [nS*nB][nH] (Hs slots 1..512)
    const unsigned short* __restrict__ Bt,  // [nI][nH]
    const float* __restrict__ bias,         // [nI]
    float* __restrict__ Y) {                // [nB][nS][nI]
  int wave = threadIdx.x >> 6, lane = threadIdx.x & 63;
  int la = lane & 15, ga = lane >> 4;
  int m0 = blockIdx.x * 64 + wave * 16;
  int n0 = blockIdx.y * 64;
  f32x4 z4 = {0.f, 0.f, 0.f, 0.f};
  f32x4 acc[4] = {z4, z4, z4, z4};
  const unsigned short* ap = A + (size_t)(m0 + la) * nH + ga * 8;
  for (int k0 = 0; k0 < nH; k0 += 32) {
    bf16x8 a = *(const bf16x8*)(ap + k0);
#pragma unroll
    for (int j = 0; j < 4; ++j) {
      bf16x8 b = *(const bf16x8*)(Bt + (size_t)(n0 + j * 16 + la) * nH + k0 + ga * 8);
      acc[j] = mfma16(a, b, acc[j]);
    }
  }
#pragma unroll
  for (int j = 0; j < 4; ++j) {
    int col = n0 + j * 16 + la;
    float bv = bias[col];
#pragma unroll
    for (int r = 0; r < 4; ++r) {
      int m = m0 + ga * 4 + r;  // m = t*32 + b
      Y[((size_t)(m & 31) * nS + (m >> 5)) * nI + col] = acc[j][r] + bv;
    }
  }
}

// ---------------- persistent recurrent kernel ----------------
// 32 WGs. WG wg owns 32 hidden columns [wg*32, wg*32+32).
//  phase A: z,r = sigmoid(H@Wzr + xp) for its 32 z-cols + 32 r-cols;
//           Z -> LDS (same-WG consumer in phase B); RH = r*H -> coherent global.
//  phase B: h~ = tanh(RH@Whh + xp); Hn = z*Hp + (1-z)*h~ ; Hp in registers.
// Latency discipline: ALL coherent loads for a phase are issued back-to-back
// as raw asm sc1 loads (ONE exposed IC round-trip per phase), then MFMAs run
// from registers with only L2-resident weight loads in the loop.
//
// Barrier: distributed per-WG monotonic flags (64B-strided, no atomic RMW).

__device__ __forceinline__ void gsync(unsigned* fl, int p) {
  asm volatile("s_waitcnt vmcnt(0) lgkmcnt(0)" ::: "memory");
  __syncthreads();
  if (threadIdx.x == 0)
    __hip_atomic_store(fl + blockIdx.x * 16, (unsigned)(p + 1),
                       __ATOMIC_RELAXED, __HIP_MEMORY_SCOPE_AGENT);
  if (threadIdx.x < 64) {
    const unsigned* f = fl + (threadIdx.x & (NW - 1)) * 16;
    unsigned v;
    do {
      v = __hip_atomic_load(f, __ATOMIC_RELAXED, __HIP_MEMORY_SCOPE_AGENT);
    } while (!__all((int)(v >= (unsigned)(p + 1))));
  }
  __syncthreads();
  asm volatile("" ::: "memory");
}

__global__ __launch_bounds__(256) void rnn_kernel(
    const unsigned short* __restrict__ XP,   // [nS][nB][N3]
    const unsigned short* __restrict__ Wzr,  // [2048][1024] = [W_hz|W_hr]^T
    const unsigned short* __restrict__ Whh,  // [1024][1024] = W_hh^T
    unsigned short* __restrict__ Hb,         // [nS+1][nB][nH] bf16 states (coherent)
    float* __restrict__ Hf,                  // [nS+1][nB][nH] fp32 states (plain, attn)
    unsigned short* __restrict__ RH,         // [nB][nH] bf16 (coherent)
    unsigned* __restrict__ fl) {             // [NW*16] barrier flags
  __shared__ float red[2][4][16][16];  // [mt][tile][row][col]
  __shared__ float zs[32][32];         // Z gate, WG-local
  int wg = blockIdx.x;
  int wave = threadIdx.x >> 6, lane = threadIdx.x & 63;
  int la = lane & 15, ga = lane >> 4;
  int kh = wave & 1, mt = wave >> 1;
  int zc = wg * 32;                    // hidden-column base for this WG
  f32x4 z4 = {0.f, 0.f, 0.f, 0.f};
  float hp[2][4] = {{0.f, 0.f, 0.f, 0.f}, {0.f, 0.f, 0.f, 0.f}};  // H prev (f32)

  // Weight row pointers (plain cached; per-WG working set ~192KB -> L2-resident),
  // pre-offset by this wave's K-half.
  const unsigned short* wz0 = Wzr + (size_t)(zc + la) * nH + ga * 8 + kh * 512;
  const unsigned short* wz1 = Wzr + (size_t)(zc + 16 + la) * nH + ga * 8 + kh * 512;
  const unsigned short* wr0 = Wzr + (size_t)(nH + zc + la) * nH + ga * 8 + kh * 512;
  const unsigned short* wr1 = Wzr + (size_t)(nH + zc + 16 + la) * nH + ga * 8 + kh * 512;
  const unsigned short* wh0 = Whh + (size_t)(zc + la) * nH + ga * 8 + kh * 512;
  const unsigned short* wh1 = Whh + (size_t)(zc + 16 + la) * nH + ga * 8 + kh * 512;

  for (int t = 0; t < nS; ++t) {
    const unsigned short* Hbase = Hb + (size_t)t * nB * nH;       // slot t
    const unsigned short* xpt = XP + (size_t)t * nB * N3;

    float xpz[2][4], xpr[2][4], xph[2][4];
    unsigned hpair[2][4];

    // ---- phase A ----
    {
      // Issue ALL coherent loads for this phase back-to-back (pipelined):
      // 16 A-fragment rows of H + 8 H-pairs for R*H.
      const unsigned short* ap = Hbase + (size_t)(mt * 16 + la) * nH + ga * 8 + kh * 512;
      bf16x8 ha[16];
#pragma unroll
      for (int i = 0; i < 16; ++i) cload16_issue(&ha[i], ap + i * 32);
      if (kh == 0) {
#pragma unroll
        for (int j = 0; j < 2; ++j) {
          int lc = j * 16 + la;
#pragma unroll
          for (int r = 0; r < 4; ++r) {
            int row = mt * 16 + ga * 4 + r;
            cload4_issue(&hpair[j][r], Hbase + (size_t)row * nH + ((zc + lc) & ~1));
          }
        }
        // XP slices (plain cached loads; covered by the same wait)
#pragma unroll
        for (int j = 0; j < 2; ++j) {
          int lc = j * 16 + la;
#pragma unroll
          for (int r = 0; r < 4; ++r) {
            int row = mt * 16 + ga * 4 + r;
            const unsigned short* xr = xpt + (size_t)row * N3;
            xpz[j][r] = b2f(xr[zc + lc]);
            xpr[j][r] = b2f(xr[nH + zc + lc]);
            xph[j][r] = b2f(xr[2 * nH + zc + lc]);
          }
        }
      }
      cwait();   // single s_waitcnt vmcnt(0) for the whole batch
      f32x4 acc[4] = {z4, z4, z4, z4};
#pragma unroll
      for (int i = 0; i < 16; ++i) {
        int k0 = i * 32;
        acc[0] = mfma16(ha[i], *(const bf16x8*)(wz0 + k0), acc[0]);
        acc[1] = mfma16(ha[i], *(const bf16x8*)(wz1 + k0), acc[1]);
        acc[2] = mfma16(ha[i], *(const bf16x8*)(wr0 + k0), acc[2]);
        acc[3] = mfma16(ha[i], *(const bf16x8*)(wr1 + k0), acc[3]);
      }
      if (kh == 1) {
#pragma unroll
        for (int j = 0; j < 4; ++j)
#pragma unroll
          for (int r = 0; r < 4; ++r) red[mt][j][ga * 4 + r][la] = acc[j][r];
      }
      __syncthreads();
      if (kh == 0) {
#pragma unroll
        for (int j = 0; j < 2; ++j) {   // z tiles
          int lc = j * 16 + la;
#pragma unroll
          for (int r = 0; r < 4; ++r) {
            int row = mt * 16 + ga * 4 + r;
            float v = acc[j][r] + red[mt][j][ga * 4 + r][la] + xpz[j][r];
            zs[row][lc] = 1.f / (1.f + __expf(-v));
          }
        }
#pragma unroll
        for (int j = 0; j < 2; ++j) {   // r tiles -> RH = r * H
          int lc = j * 16 + la;
          int hc = zc + lc;
#pragma unroll
          for (int r = 0; r < 4; ++r) {
            int row = mt * 16 + ga * 4 + r;
            float v = acc[j + 2][r] + red[mt][j + 2][ga * 4 + r][la] + xpr[j][r];
            float rs = 1.f / (1.f + __expf(-v));
            unsigned pair = hpair[j][r];
            float h = b2f((unsigned short)((la & 1) ? (pair >> 16) : (pair & 0xffffu)));
            float rhv = rs * h;
            float other = __shfl_xor(rhv, 1);
            if (!(la & 1))
              cstore4(RH + (size_t)row * nH + hc,
                      (unsigned)f2b(rhv) | ((unsigned)f2b(other) << 16));
          }
        }
      }
    }
    gsync(fl, 2 * t);
    // ---- phase B ----
    {
      // Batch all 16 A-fragment coherent loads (RH rows), pipelined.
      const unsigned short* ap = RH + (size_t)(mt * 16 + la) * nH + ga * 8 + kh * 512;
      bf16x8 rb[16];
#pragma unroll
      for (int i = 0; i < 16; ++i) cload16_issue(&rb[i], ap + i * 32);
      cwait();
      f32x4 acc[2] = {z4, z4};
#pragma unroll
      for (int i = 0; i < 16; ++i) {
        int k0 = i * 32;
        acc[0] = mfma16(rb[i], *(const bf16x8*)(wh0 + k0), acc[0]);
        acc[1] = mfma16(rb[i], *(const bf16x8*)(wh1 + k0), acc[1]);
      }
      if (kh == 1) {
#pragma unroll
        for (int j = 0; j < 2; ++j)
#pragma unroll
          for (int r = 0; r < 4; ++r) red[mt][j][ga * 4 + r][la] = acc[j][r];
      }
      __syncthreads();
      if (kh == 0) {
#pragma unroll
        for (int j = 0; j < 2; ++j) {
          int lc = j * 16 + la;
          int col = zc + lc;
#pragma unroll
          for (int r = 0; r < 4; ++r) {
            int row = mt * 16 + ga * 4 + r;
            float v = acc[j][r] + red[mt][j][ga * 4 + r][la] + xph[j][r];
            float ht = tanhf(v);
            float z = zs[row][lc];
            float hn = z * hp[j][r] + (1.f - z) * ht;
            hp[j][r] = hn;
            Hf[(size_t)(t + 1) * nB * nH + (size_t)row * nH + col] = hn;  // plain (attn)
            float other = __shfl_xor(hn, 1);
            if (!(la & 1))
              cstore4(Hb + (size_t)(t + 1) * nB * nH + (size_t)row * nH + col,
                      (unsigned)f2b(hn) | ((unsigned)f2b(other) << 16));
          }
        }
      }
    }
    gsync(fl, 2 * t + 1);
  }
}

// ---------------- attention pooling ----------------
__global__ __launch_bounds__(256) void attn_kernel(
    const float* __restrict__ Hf,      // [nS+1][nB][nH], slots 1..512
    const float* __restrict__ attn_W,  // [nH]
    const float* __restrict__ attn_b,  // [1]
    float* __restrict__ out_ctx,       // [nB][nH]
    float* __restrict__ out_aw) {      // [nB][nS]
  int b = blockIdx.x;
  int tid = threadIdx.x;
  int wave = tid >> 6, lane = tid & 63;
  __shared__ float e[nS];
  __shared__ float red4[4];
  float abias = attn_b[0];
  for (int s = wave; s < nS; s += 4) {
    const float* h = Hf + ((size_t)(s + 1) * nB + b) * nH;
    float p = 0.f;
    for (int k = lane; k < nH; k += 64) p += h[k] * attn_W[k];
#pragma unroll
    for (int off = 32; off > 0; off >>= 1) p += __shfl_down(p, off);
    if (lane == 0) e[s] = tanhf(p + abias);
  }
  __syncthreads();
  float m = -1e30f;
  for (int s = tid; s < nS; s += 256) m = fmaxf(m, e[s]);
#pragma unroll
  for (int off = 32; off > 0; off >>= 1) m = fmaxf(m, __shfl_down(m, off));
  if (lane == 0) red4[wave] = m;
  __syncthreads();
  float M = fmaxf(fmaxf(red4[0], red4[1]), fmaxf(red4[2], red4[3]));
  __syncthreads();
  float ssum = 0.f;
  for (int s = tid; s < nS; s += 256) {
    float w = __expf(e[s] - M);
    e[s] = w;
    ssum += w;
  }
#pragma unroll
  for (int off = 32; off > 0; off >>= 1) ssum += __shfl_down(ssum, off);
  if (lane == 0) red4[wave] = ssum;
  __syncthreads();
  float inv = 1.f / (red4[0] + red4[1] + red4[2] + red4[3]);
  for (int s = tid; s < nS; s += 256) out_aw[b * nS + s] = e[s] * inv;
  int col = tid * 4;
  float4 c = {0.f, 0.f, 0.f, 0.f};
  for (int s = 0; s < nS; ++s) {
    float w = e[s] * inv;
    float4 hv = *(const float4*)(Hf + ((size_t)(s + 1) * nB + b) * nH + col);
    c.x += w * hv.x; c.y += w * hv.y; c.z += w * hv.z; c.w += w * hv.w;
  }
  *(float4*)(out_ctx + (size_t)b * nH + col) = c;
}

// ---------------- launcher ----------------
extern "C" void kernel_launch(void* const* d_in, const int* in_sizes, int n_in,
                              void* d_out, int out_size, void* d_ws, size_t ws_size,
                              hipStream_t stream) {
  const float* x      = (const float*)d_in[0];
  const float* W_xz   = (const float*)d_in[1];
  const float* W_hz   = (const float*)d_in[2];
  const float* b_z    = (const float*)d_in[3];
  const float* W_xr   = (const float*)d_in[4];
  const float* W_hr   = (const float*)d_in[5];
  const float* b_r    = (const float*)d_in[6];
  const float* W_xh   = (const float*)d_in[7];
  const float* W_hh   = (const float*)d_in[8];
  const float* b_h    = (const float*)d_in[9];
  const float* W_hq   = (const float*)d_in[10];
  const float* b_q    = (const float*)d_in[11];
  const float* attn_W = (const float*)d_in[12];
  const float* attn_b = (const float*)d_in[13];

  char* ws = (char*)d_ws;
  unsigned short* xb  = (unsigned short*)(ws + 0);          // 16,777,216
  unsigned short* wx  = (unsigned short*)(ws + 16777216);   //  3,145,728
  float*          bc  = (float*)         (ws + 19922944);   //     12,288
  unsigned short* wzr = (unsigned short*)(ws + 19935232);   //  4,194,304
  unsigned short* whh = (unsigned short*)(ws + 24129536);   //  2,097,152
  unsigned short* whq = (unsigned short*)(ws + 26226688);   //  1,048,576
  unsigned short* xp  = (unsigned short*)(ws + 27275264);   // 100,663,296
  unsigned short* hb  = (unsigned short*)(ws + 127938560);  // 33,619,968
  float*          hf  = (float*)         (ws + 161558528);  // 67,239,936
  unsigned short* rh  = (unsigned short*)(ws + 228798464);  //     65,536
  unsigned*       fl  = (unsigned*)      (ws + 228864000);  //      4,096

  float* out_y   = (float*)d_out;             // [32][512][512]
  float* out_ctx = (float*)d_out + 8388608;   // [32][1024]
  float* out_aw  = (float*)d_out + 8421376;   // [32][512]

  cast_x_kernel<<<dim3(8192), dim3(256), 0, stream>>>(x, xb);
  tcast_kernel<<<dim3(nH/32, nI/32), dim3(256), 0, stream>>>(W_xz, wx, nI, nH);
  tcast_kernel<<<dim3(nH/32, nI/32), dim3(256), 0, stream>>>(W_xr, wx + 1024*512, nI, nH);
  tcast_kernel<<<dim3(nH/32, nI/32), dim3(256), 0, stream>>>(W_xh, wx + 2048*512, nI, nH);
  tcast_kernel<<<dim3(nH/32, nH/32), dim3(256), 0, stream>>>(W_hz, wzr, nH, nH);
  tcast_kernel<<<dim3(nH/32, nH/32), dim3(256), 0, stream>>>(W_hr, wzr + 1024*1024, nH, nH);
  tcast_kernel<<<dim3(nH/32, nH/32), dim3(256), 0, stream>>>(W_hh, whh, nH, nH);
  tcast_kernel<<<dim3(nI/32, nH/32), dim3(256), 0, stream>>>(W_hq, whq, nH, nI);
  bias_cat_kernel<<<dim3(12), dim3(256), 0, stream>>>(b_z, b_r, b_h, bc);
  init_kernel<<<dim3(128), dim3(256), 0, stream>>>(hb, fl);

  gemm_xp_kernel<<<dim3(256, 48), dim3(256), 0, stream>>>(xb, wx, bc, xp);
  rnn_kernel<<<dim3(NW), dim3(256), 0, stream>>>(xp, wzr, whh, hb, hf, rh, fl);
  gemm_y_kernel<<<dim3(256, 8), dim3(256), 0, stream>>>(hb + nB * nH, whq, b_q, out_y);
  attn_kernel<<<dim3(nB), dim3(256), 0, stream>>>(hf, attn_W, attn_b, out_ctx, out_aw);
}

// Round 7
// 7728.725 us; speedup vs baseline: 1.4755x; 1.4755x over previous
//
#include <hip/hip_runtime.h>

// Problem dims
constexpr int nB = 32, nS = 512, nI = 512, nH = 1024;
constexpr int N3 = 3 * nH;   // z|r|h concat
constexpr int NW = 32;       // rnn persistent workgroups

typedef __attribute__((ext_vector_type(8))) __bf16 bf16x8;
typedef __attribute__((ext_vector_type(4))) float f32x4;
typedef __attribute__((ext_vector_type(8))) unsigned short u16x8;
typedef __attribute__((ext_vector_type(4))) unsigned short u16x4;

__device__ __forceinline__ f32x4 mfma16(bf16x8 a, bf16x8 b, f32x4 c) {
  return __builtin_amdgcn_mfma_f32_16x16x32_bf16(a, b, c, 0, 0, 0);
}

// RNE float->bf16
__device__ __forceinline__ unsigned short f2b(float f) {
  unsigned u = __float_as_uint(f);
  u += 0x7fffu + ((u >> 16) & 1u);
  return (unsigned short)(u >> 16);
}
__device__ __forceinline__ float b2f(unsigned short s) {
  return __uint_as_float(((unsigned)s) << 16);
}

// Cross-WG coherence scheme (no cache maintenance in the loop):
//  - Producers store shared data with sc1 (write-through at the IC).
//  - Consumers use PLAIN CACHED loads. Safe because every shared address is
//    written exactly once per run BEFORE its first read (Hb ring over t, RH
//    ring over t), and kernel-launch acquire invalidated L2 — so first touch
//    fetches the sc1-written value from IC and siblings on the XCD hit L2.
__device__ __forceinline__ void cstore4(unsigned short* p, unsigned v) {
  __hip_atomic_store((unsigned*)p, v, __ATOMIC_RELAXED, __HIP_MEMORY_SCOPE_AGENT);
}

// ---------------- prep kernels ----------------

__global__ __launch_bounds__(256) void cast_x_kernel(const float* __restrict__ x,
                                                     unsigned short* __restrict__ xb) {
  size_t i = (size_t)blockIdx.x * 256 + threadIdx.x;
  float4 v = ((const float4*)x)[i];
  uint2 o;
  o.x = (unsigned)f2b(v.x) | ((unsigned)f2b(v.y) << 16);
  o.y = (unsigned)f2b(v.z) | ((unsigned)f2b(v.w) << 16);
  *(uint2*)(xb + i * 4) = o;
}

// out[n][k] = bf16(in[k][n]); in: [K][N] f32. 32x32 LDS tile transpose.
__global__ __launch_bounds__(256) void tcast_kernel(const float* __restrict__ in,
                                                    unsigned short* __restrict__ out,
                                                    int K, int N) {
  __shared__ float tile[32][33];
  int tn = blockIdx.x * 32, tk = blockIdx.y * 32;
  int lx = threadIdx.x & 31, ly = threadIdx.x >> 5;
#pragma unroll
  for (int r = ly; r < 32; r += 8)
    tile[r][lx] = in[(size_t)(tk + r) * N + tn + lx];
  __syncthreads();
#pragma unroll
  for (int r = ly; r < 32; r += 8)
    out[(size_t)(tn + r) * K + tk + lx] = f2b(tile[lx][r]);
}

__global__ __launch_bounds__(256) void bias_cat_kernel(const float* __restrict__ bz,
                                                       const float* __restrict__ br,
                                                       const float* __restrict__ bh,
                                                       float* __restrict__ bc) {
  int i = blockIdx.x * 256 + threadIdx.x;
  if (i >= N3) return;
  bc[i] = (i < nH) ? bz[i] : (i < 2 * nH ? br[i - nH] : bh[i - 2 * nH]);
}

__global__ __launch_bounds__(256) void init_kernel(unsigned short* __restrict__ hb0,
                                                   unsigned* __restrict__ fl) {
  int i = blockIdx.x * 256 + threadIdx.x;   // grid 128 -> 32768 threads
  hb0[i] = 0;                               // H0 = 0 (32*1024 elems)
  if (i < 1024) fl[i] = 0u;                 // barrier flags (NW*16 used)
}

// ---------------- big parallel GEMMs (bf16 MFMA 16x16x32) ----------------
// A fragment: lane l -> A[row0 + (l&15)][k0 + (l>>4)*8 + e]
// B fragment (Bt = B^T, [N][K]): lane l -> B[k0 + (l>>4)*8 + e][n0 + (l&15)]
// D: lane l, reg r -> D[(l>>4)*4 + r][l&15]

__global__ __launch_bounds__(256) void gemm_xp_kernel(
    const unsigned short* __restrict__ A,   // [nB*nS][nI]  (row m = b*nS + s)
    const unsigned short* __restrict__ Bt,  // [N3][nI]
    const float* __restrict__ bias,         // [N3]
    unsigned short* __restrict__ XP) {      // [nS][nB][N3]
  int wave = threadIdx.x >> 6, lane = threadIdx.x & 63;
  int la = lane & 15, ga = lane >> 4;
  int m0 = blockIdx.x * 64 + wave * 16;
  int n0 = blockIdx.y * 64;
  f32x4 z4 = {0.f, 0.f, 0.f, 0.f};
  f32x4 acc[4] = {z4, z4, z4, z4};
  const unsigned short* ap = A + (size_t)(m0 + la) * nI + ga * 8;
  for (int k0 = 0; k0 < nI; k0 += 32) {
    bf16x8 a = *(const bf16x8*)(ap + k0);
#pragma unroll
    for (int j = 0; j < 4; ++j) {
      bf16x8 b = *(const bf16x8*)(Bt + (size_t)(n0 + j * 16 + la) * nI + k0 + ga * 8);
      acc[j] = mfma16(a, b, acc[j]);
    }
  }
#pragma unroll
  for (int j = 0; j < 4; ++j) {
    int col = n0 + j * 16 + la;
    float bv = bias[col];
#pragma unroll
    for (int r = 0; r < 4; ++r) {
      int m = m0 + ga * 4 + r;
      int s = m & (nS - 1), bi = m >> 9;
      XP[((size_t)s * nB + bi) * N3 + col] = f2b(acc[j][r] + bv);
    }
  }
}

__global__ __launch_bounds__(256) void gemm_y_kernel(
    const unsigned short* __restrict__ A,   // [nS*nB][nH] (Hs slots 1..512)
    const unsigned short* __restrict__ Bt,  // [nI][nH]
    const float* __restrict__ bias,         // [nI]
    float* __restrict__ Y) {                // [nB][nS][nI]
  int wave = threadIdx.x >> 6, lane = threadIdx.x & 63;
  int la = lane & 15, ga = lane >> 4;
  int m0 = blockIdx.x * 64 + wave * 16;
  int n0 = blockIdx.y * 64;
  f32x4 z4 = {0.f, 0.f, 0.f, 0.f};
  f32x4 acc[4] = {z4, z4, z4, z4};
  const unsigned short* ap = A + (size_t)(m0 + la) * nH + ga * 8;
  for (int k0 = 0; k0 < nH; k0 += 32) {
    bf16x8 a = *(const bf16x8*)(ap + k0);
#pragma unroll
    for (int j = 0; j < 4; ++j) {
      bf16x8 b = *(const bf16x8*)(Bt + (size_t)(n0 + j * 16 + la) * nH + k0 + ga * 8);
      acc[j] = mfma16(a, b, acc[j]);
    }
  }
#pragma unroll
  for (int j = 0; j < 4; ++j) {
    int col = n0 + j * 16 + la;
    float bv = bias[col];
#pragma unroll
    for (int r = 0; r < 4; ++r) {
      int m = m0 + ga * 4 + r;  // m = t*32 + b
      Y[((size_t)(m & 31) * nS + (m >> 5)) * nI + col] = acc[j][r] + bv;
    }
  }
}

// ---------------- persistent recurrent kernel ----------------
// 32 WGs. WG wg owns 32 hidden columns [wg*32, wg*32+32).
//  phase A: z,r = sigmoid(H@Wzr + xp) for its 32 z-cols + 32 r-cols;
//           Z -> LDS (same-WG consumer in phase B); RH = r*H -> RH ring (sc1).
//  phase B: h~ = tanh(RH@Whh + xp); Hn = z*Hp + (1-z)*h~ ; Hp in registers.
// Consumers read H / RH with PLAIN CACHED loads (write-once rings make this
// safe; see scheme note above) -> first touch per XCD hits IC, rest hit L2,
// and the compiler pipelines the loads normally.
//
// Barrier: distributed per-WG monotonic flags (64B-strided, sc1, no RMW).

__device__ __forceinline__ void gsync(unsigned* fl, int p) {
  asm volatile("s_waitcnt vmcnt(0) lgkmcnt(0)" ::: "memory");
  __syncthreads();
  if (threadIdx.x == 0)
    __hip_atomic_store(fl + blockIdx.x * 16, (unsigned)(p + 1),
                       __ATOMIC_RELAXED, __HIP_MEMORY_SCOPE_AGENT);
  if (threadIdx.x < 64) {
    const unsigned* f = fl + (threadIdx.x & (NW - 1)) * 16;
    unsigned v;
    do {
      v = __hip_atomic_load(f, __ATOMIC_RELAXED, __HIP_MEMORY_SCOPE_AGENT);
    } while (!__all((int)(v >= (unsigned)(p + 1))));
  }
  __syncthreads();
  asm volatile("" ::: "memory");
}

__global__ __launch_bounds__(256) void rnn_kernel(
    const unsigned short* __restrict__ XP,   // [nS][nB][N3]
    const unsigned short* __restrict__ Wzr,  // [2048][1024] = [W_hz|W_hr]^T
    const unsigned short* __restrict__ Whh,  // [1024][1024] = W_hh^T
    unsigned short* __restrict__ Hb,         // [nS+1][nB][nH] bf16 states (ring)
    unsigned short* __restrict__ RH,         // [nS][nB][nH] bf16 (ring)
    unsigned* __restrict__ fl) {             // [NW*16] barrier flags
  __shared__ float red[2][4][16][16];  // [mt][tile][row][col]
  __shared__ float zs[32][32];         // Z gate, WG-local
  int wg = blockIdx.x;
  int wave = threadIdx.x >> 6, lane = threadIdx.x & 63;
  int la = lane & 15, ga = lane >> 4;
  int kh = wave & 1, mt = wave >> 1;
  int zc = wg * 32;                    // hidden-column base for this WG
  f32x4 z4 = {0.f, 0.f, 0.f, 0.f};
  float hp[2][4] = {{0.f, 0.f, 0.f, 0.f}, {0.f, 0.f, 0.f, 0.f}};  // H prev (f32)

  // Weight row pointers (plain cached; per-WG working set ~192KB -> L2-resident),
  // pre-offset by this wave's K-half.
  const unsigned short* wz0 = Wzr + (size_t)(zc + la) * nH + ga * 8 + kh * 512;
  const unsigned short* wz1 = Wzr + (size_t)(zc + 16 + la) * nH + ga * 8 + kh * 512;
  const unsigned short* wr0 = Wzr + (size_t)(nH + zc + la) * nH + ga * 8 + kh * 512;
  const unsigned short* wr1 = Wzr + (size_t)(nH + zc + 16 + la) * nH + ga * 8 + kh * 512;
  const unsigned short* wh0 = Whh + (size_t)(zc + la) * nH + ga * 8 + kh * 512;
  const unsigned short* wh1 = Whh + (size_t)(zc + 16 + la) * nH + ga * 8 + kh * 512;

  for (int t = 0; t < nS; ++t) {
    const unsigned short* Hbase = Hb + (size_t)t * nB * nH;        // slot t
    unsigned short* RHs = RH + ((size_t)t * nB * nH);              // ring slot t
    const unsigned short* xpt = XP + (size_t)t * nB * N3;

    float xpz[2][4], xpr[2][4], xph[2][4];
    unsigned hpair[2][4];

    // ---- phase A ----
    {
      // All consumer loads are PLAIN -> compiler pipelines them freely.
      const unsigned short* ap = Hbase + (size_t)(mt * 16 + la) * nH + ga * 8 + kh * 512;
      bf16x8 ha[16];
#pragma unroll
      for (int i = 0; i < 16; ++i) ha[i] = *(const bf16x8*)(ap + i * 32);
      if (kh == 0) {
#pragma unroll
        for (int j = 0; j < 2; ++j) {
          int lc = j * 16 + la;
#pragma unroll
          for (int r = 0; r < 4; ++r) {
            int row = mt * 16 + ga * 4 + r;
            hpair[j][r] = *(const unsigned*)(Hbase + (size_t)row * nH + ((zc + lc) & ~1));
            const unsigned short* xr = xpt + (size_t)row * N3;
            xpz[j][r] = b2f(xr[zc + lc]);
            xpr[j][r] = b2f(xr[nH + zc + lc]);
            xph[j][r] = b2f(xr[2 * nH + zc + lc]);
          }
        }
      }
      f32x4 acc[4] = {z4, z4, z4, z4};
#pragma unroll
      for (int i = 0; i < 16; ++i) {
        int k0 = i * 32;
        acc[0] = mfma16(ha[i], *(const bf16x8*)(wz0 + k0), acc[0]);
        acc[1] = mfma16(ha[i], *(const bf16x8*)(wz1 + k0), acc[1]);
        acc[2] = mfma16(ha[i], *(const bf16x8*)(wr0 + k0), acc[2]);
        acc[3] = mfma16(ha[i], *(const bf16x8*)(wr1 + k0), acc[3]);
      }
      if (kh == 1) {
#pragma unroll
        for (int j = 0; j < 4; ++j)
#pragma unroll
          for (int r = 0; r < 4; ++r) red[mt][j][ga * 4 + r][la] = acc[j][r];
      }
      __syncthreads();
      if (kh == 0) {
#pragma unroll
        for (int j = 0; j < 2; ++j) {   // z tiles
          int lc = j * 16 + la;
#pragma unroll
          for (int r = 0; r < 4; ++r) {
            int row = mt * 16 + ga * 4 + r;
            float v = acc[j][r] + red[mt][j][ga * 4 + r][la] + xpz[j][r];
            zs[row][lc] = 1.f / (1.f + __expf(-v));
          }
        }
#pragma unroll
        for (int j = 0; j < 2; ++j) {   // r tiles -> RH = r * H
          int lc = j * 16 + la;
          int hc = zc + lc;
#pragma unroll
          for (int r = 0; r < 4; ++r) {
            int row = mt * 16 + ga * 4 + r;
            float v = acc[j + 2][r] + red[mt][j + 2][ga * 4 + r][la] + xpr[j][r];
            float rs = 1.f / (1.f + __expf(-v));
            unsigned pair = hpair[j][r];
            float h = b2f((unsigned short)((la & 1) ? (pair >> 16) : (pair & 0xffffu)));
            float rhv = rs * h;
            float other = __shfl_xor(rhv, 1);
            if (!(la & 1))
              cstore4(RHs + (size_t)row * nH + hc,
                      (unsigned)f2b(rhv) | ((unsigned)f2b(other) << 16));
          }
        }
      }
    }
    gsync(fl, 2 * t);
    // ---- phase B ----
    {
      const unsigned short* ap = RHs + (size_t)(mt * 16 + la) * nH + ga * 8 + kh * 512;
      bf16x8 rb[16];
#pragma unroll
      for (int i = 0; i < 16; ++i) rb[i] = *(const bf16x8*)(ap + i * 32);
      f32x4 acc[2] = {z4, z4};
#pragma unroll
      for (int i = 0; i < 16; ++i) {
        int k0 = i * 32;
        acc[0] = mfma16(rb[i], *(const bf16x8*)(wh0 + k0), acc[0]);
        acc[1] = mfma16(rb[i], *(const bf16x8*)(wh1 + k0), acc[1]);
      }
      if (kh == 1) {
#pragma unroll
        for (int j = 0; j < 2; ++j)
#pragma unroll
          for (int r = 0; r < 4; ++r) red[mt][j][ga * 4 + r][la] = acc[j][r];
      }
      __syncthreads();
      if (kh == 0) {
#pragma unroll
        for (int j = 0; j < 2; ++j) {
          int lc = j * 16 + la;
          int col = zc + lc;
#pragma unroll
          for (int r = 0; r < 4; ++r) {
            int row = mt * 16 + ga * 4 + r;
            float v = acc[j][r] + red[mt][j][ga * 4 + r][la] + xph[j][r];
            float ht = tanhf(v);
            float z = zs[row][lc];
            float hn = z * hp[j][r] + (1.f - z) * ht;
            hp[j][r] = hn;
            float other = __shfl_xor(hn, 1);
            if (!(la & 1))
              cstore4(Hb + (size_t)(t + 1) * nB * nH + (size_t)row * nH + col,
                      (unsigned)f2b(hn) | ((unsigned)f2b(other) << 16));
          }
        }
      }
    }
    gsync(fl, 2 * t + 1);
  }
}

// ---------------- attention pooling (reads bf16 Hb, slots 1..512) ----------------
__global__ __launch_bounds__(256) void attn_kernel(
    const unsigned short* __restrict__ Hb,  // [nS+1][nB][nH]
    const float* __restrict__ attn_W,  // [nH]
    const float* __restrict__ attn_b,  // [1]
    float* __restrict__ out_ctx,       // [nB][nH]
    float* __restrict__ out_aw) {      // [nB][nS]
  int b = blockIdx.x;
  int tid = threadIdx.x;
  int wave = tid >> 6, lane = tid & 63;
  __shared__ float e[nS];
  __shared__ float red4[4];
  float abias = attn_b[0];
  for (int s = wave; s < nS; s += 4) {
    const unsigned short* h = Hb + ((size_t)(s + 1) * nB + b) * nH + lane * 16;
    const float* w = attn_W + lane * 16;
    u16x8 v0 = *(const u16x8*)(h);
    u16x8 v1 = *(const u16x8*)(h + 8);
    float p = 0.f;
#pragma unroll
    for (int k = 0; k < 8; ++k) p += b2f(v0[k]) * w[k];
#pragma unroll
    for (int k = 0; k < 8; ++k) p += b2f(v1[k]) * w[k + 8];
#pragma unroll
    for (int off = 32; off > 0; off >>= 1) p += __shfl_down(p, off);
    if (lane == 0) e[s] = tanhf(p + abias);
  }
  __syncthreads();
  float m = -1e30f;
  for (int s = tid; s < nS; s += 256) m = fmaxf(m, e[s]);
#pragma unroll
  for (int off = 32; off > 0; off >>= 1) m = fmaxf(m, __shfl_down(m, off));
  if (lane == 0) red4[wave] = m;
  __syncthreads();
  float M = fmaxf(fmaxf(red4[0], red4[1]), fmaxf(red4[2], red4[3]));
  __syncthreads();
  float ssum = 0.f;
  for (int s = tid; s < nS; s += 256) {
    float w = __expf(e[s] - M);
    e[s] = w;
    ssum += w;
  }
#pragma unroll
  for (int off = 32; off > 0; off >>= 1) ssum += __shfl_down(ssum, off);
  if (lane == 0) red4[wave] = ssum;
  __syncthreads();
  float inv = 1.f / (red4[0] + red4[1] + red4[2] + red4[3]);
  for (int s = tid; s < nS; s += 256) out_aw[b * nS + s] = e[s] * inv;
  int col = tid * 4;
  float4 c = {0.f, 0.f, 0.f, 0.f};
  for (int s = 0; s < nS; ++s) {
    float w = e[s] * inv;
    u16x4 q = *(const u16x4*)(Hb + ((size_t)(s + 1) * nB + b) * nH + col);
    c.x += w * b2f(q[0]); c.y += w * b2f(q[1]);
    c.z += w * b2f(q[2]); c.w += w * b2f(q[3]);
  }
  *(float4*)(out_ctx + (size_t)b * nH + col) = c;
}

// ---------------- launcher ----------------
extern "C" void kernel_launch(void* const* d_in, const int* in_sizes, int n_in,
                              void* d_out, int out_size, void* d_ws, size_t ws_size,
                              hipStream_t stream) {
  const float* x      = (const float*)d_in[0];
  const float* W_xz   = (const float*)d_in[1];
  const float* W_hz   = (const float*)d_in[2];
  const float* b_z    = (const float*)d_in[3];
  const float* W_xr   = (const float*)d_in[4];
  const float* W_hr   = (const float*)d_in[5];
  const float* b_r    = (const float*)d_in[6];
  const float* W_xh   = (const float*)d_in[7];
  const float* W_hh   = (const float*)d_in[8];
  const float* b_h    = (const float*)d_in[9];
  const float* W_hq   = (const float*)d_in[10];
  const float* b_q    = (const float*)d_in[11];
  const float* attn_W = (const float*)d_in[12];
  const float* attn_b = (const float*)d_in[13];

  char* ws = (char*)d_ws;
  unsigned short* xb  = (unsigned short*)(ws + 0);          // 16,777,216
  unsigned short* wx  = (unsigned short*)(ws + 16777216);   //  3,145,728
  float*          bc  = (float*)         (ws + 19922944);   //     12,288
  unsigned short* wzr = (unsigned short*)(ws + 19935232);   //  4,194,304
  unsigned short* whh = (unsigned short*)(ws + 24129536);   //  2,097,152
  unsigned short* whq = (unsigned short*)(ws + 26226688);   //  1,048,576
  unsigned short* xp  = (unsigned short*)(ws + 27275264);   // 100,663,296
  unsigned short* hb  = (unsigned short*)(ws + 127938560);  // 33,619,968
  unsigned short* rh  = (unsigned short*)(ws + 161558528);  // 33,554,432 (ring)
  unsigned*       fl  = (unsigned*)      (ws + 195112960);  //      4,096

  float* out_y   = (float*)d_out;             // [32][512][512]
  float* out_ctx = (float*)d_out + 8388608;   // [32][1024]
  float* out_aw  = (float*)d_out + 8421376;   // [32][512]

  cast_x_kernel<<<dim3(8192), dim3(256), 0, stream>>>(x, xb);
  tcast_kernel<<<dim3(nH/32, nI/32), dim3(256), 0, stream>>>(W_xz, wx, nI, nH);
  tcast_kernel<<<dim3(nH/32, nI/32), dim3(256), 0, stream>>>(W_xr, wx + 1024*512, nI, nH);
  tcast_kernel<<<dim3(nH/32, nI/32), dim3(256), 0, stream>>>(W_xh, wx + 2048*512, nI, nH);
  tcast_kernel<<<dim3(nH/32, nH/32), dim3(256), 0, stream>>>(W_hz, wzr, nH, nH);
  tcast_kernel<<<dim3(nH/32, nH/32), dim3(256), 0, stream>>>(W_hr, wzr + 1024*1024, nH, nH);
  tcast_kernel<<<dim3(nH/32, nH/32), dim3(256), 0, stream>>>(W_hh, whh, nH, nH);
  tcast_kernel<<<dim3(nI/32, nH/32), dim3(256), 0, stream>>>(W_hq, whq, nH, nI);
  bias_cat_kernel<<<dim3(12), dim3(256), 0, stream>>>(b_z, b_r, b_h, bc);
  init_kernel<<<dim3(128), dim3(256), 0, stream>>>(hb, fl);

  gemm_xp_kernel<<<dim3(256, 48), dim3(256), 0, stream>>>(xb, wx, bc, xp);
  rnn_kernel<<<dim3(NW), dim3(256), 0, stream>>>(xp, wzr, whh, hb, rh, fl);
  gemm_y_kernel<<<dim3(256, 8), dim3(256), 0, stream>>>(hb + nB * nH, whq, b_q, out_y);
  attn_kernel<<<dim3(nB), dim3(256), 0, stream>>>(hb, attn_W, attn_b, out_ctx, out_aw);
}